// Round 5
// baseline (237.321 us; speedup 1.0000x reference)
//
#include <hip/hip_runtime.h>

// PCEN: x (32,128,8000) f32, log_s (128,) f32 -> out (32,128,8000) f32
//   s = exp(log_s[f]); a = 1-s
//   M[t] = a*M[t-1] + s*x[t], M[0] = x[0]
//   out  = sqrt(x * (1e-6 + M)^-0.98 + 2) - sqrt(2)
//
// One wave per CHUNK of a sequence (4 chunks/seq => 16384 waves). Chunks >0
// rebuild incoming IIR state from a 768-elem halo (a^768 ~ 3.6e-9 << fp32
// noise). Wave-level weighted prefix scan is done ENTIRELY with DPP
// (row_shr + row_bcast15/31) -- zero LDS/bpermute traffic, which was the
// R4 bottleneck (8 ds_bpermute+lgkmcnt per iter saturated the LDS pipe).
// Carry broadcast via v_readlane. float4/lane, 3-deep prefetch ring.

#define T_LEN 8000
#define F_DIM 128
#define NSEQ  4096          // B*F
#define CHUNK 2048          // outputs per chunk (chunk 3: 1856 = 7*256 + 64 tail)
#define HALO_ITERS 3        // 768-element warm-up

typedef __attribute__((ext_vector_type(4))) float vfloat4;  // for NT store

// NOTE: __builtin_amdgcn_logf IS log2 (see __clang_hip_math.h __log2f)
__device__ __forceinline__ float hw_log2(float v) { return __builtin_amdgcn_logf(v); }
__device__ __forceinline__ float hw_exp2(float v) { return __builtin_amdgcn_exp2f(v); }

__device__ __forceinline__ float pcen_out(float xi, float m) {
    float p = hw_exp2(-0.98f * hw_log2(1e-6f + m));
    return __builtin_amdgcn_sqrtf(fmaf(xi, p, 2.0f)) - 1.4142135623730951f;
}

// DPP move: masked-out / invalid source lanes yield 0 (old = 0).
template<int CTRL, int ROWMASK>
__device__ __forceinline__ float dppf(float v) {
    int r = __builtin_amdgcn_update_dpp(0, __float_as_int(v), CTRL, ROWMASK, 0xF, false);
    return __int_as_float(r);
}

__device__ __forceinline__ float lane63(float v) {
    return __int_as_float(__builtin_amdgcn_readlane(__float_as_int(v), 63));
}

// Weighted inclusive wave scan, per-lane decay ratio r: P[l] = sum_j r^(l-j) B[j].
// ck = r^(2^k) scalars; w15 = r^((lane&31)-15), w31 = r^(lane-31) per-lane VGPRs.
__device__ __forceinline__ float wave_scan(float B, float ck0, float ck1, float ck2,
                                           float ck3, float w15, float w31) {
    float P = B;
    P = fmaf(ck0, dppf<0x111, 0xF>(P), P);   // row_shr:1
    P = fmaf(ck1, dppf<0x112, 0xF>(P), P);   // row_shr:2
    P = fmaf(ck2, dppf<0x114, 0xF>(P), P);   // row_shr:4
    P = fmaf(ck3, dppf<0x118, 0xF>(P), P);   // row_shr:8
    P = fmaf(w15, dppf<0x142, 0xA>(P), P);   // row_bcast15 -> rows 1,3
    P = fmaf(w31, dppf<0x143, 0xC>(P), P);   // row_bcast31 -> rows 2,3
    return P;
}

__global__ __launch_bounds__(256) void pcen_kernel(const float* __restrict__ x,
                                                   const float* __restrict__ log_s,
                                                   float* __restrict__ out) {
    const int lane  = threadIdx.x & 63;
    const int wid   = blockIdx.x * 4 + (threadIdx.x >> 6);
    const int seq   = wid >> 2;          // b*128 + f
    const int chunk = wid & 3;
    const int f     = seq & (F_DIM - 1);

    const float* xp = x   + (size_t)seq * T_LEN;
    float*       op = out + (size_t)seq * T_LEN;

    const float s    = hw_exp2(log_s[f] * 1.4426950408889634f);
    const float a    = 1.0f - s;
    const float invA = 1.0f / a;
    const float l2a  = hw_log2(a);

    const float a2 = a * a;
    const float a4 = a2 * a2;
    // main scan: ratio r = a^4
    const float c0 = a4;        // r
    const float c1 = c0 * c0;   // r^2  = a^8
    const float c2 = c1 * c1;   // r^4  = a^16
    const float c3 = c2 * c2;   // r^8  = a^32
    const float a256 = c3 * c3 * c3 * c3; // a^256... (a^32)^8
    const int   lm31 = lane & 31;
    const float w15  = hw_exp2((float)(4 * (lm31 - 15)) * l2a); // a^(4((lane&31)-15))
    const float w31  = hw_exp2((float)(4 * (lane - 31)) * l2a); // a^(4(lane-31))
    const float a4l1 = hw_exp2((float)(4 * (lane + 1)) * l2a);  // a^(4(lane+1))

    const int S     = chunk * CHUNK;
    const int halo  = (chunk == 0) ? 0 : HALO_ITERS;
    const int mains = (chunk < 3) ? (CHUNK / 256) : 7;   // chunk3: 7*256, +64 tail
    const int total = halo + mains;
    const int base  = S - halo * 256;

    float carry = (chunk == 0) ? xp[0] : 0.0f;   // truncated state for chunks>0

    const float4* xv4 = (const float4*)(xp + base);
    vfloat4*      ov4 = (vfloat4*)(op + base);

    // 3-deep prefetch ring (total >= 8 always)
    float4 p0 = xv4[0 * 64 + lane];
    float4 p1 = xv4[1 * 64 + lane];
    float4 p2 = xv4[2 * 64 + lane];

    #pragma unroll 1
    for (int it = 0; it < total; ++it) {
        float4 xv = p0;
        p0 = p1; p1 = p2;
        if (it + 3 < total) p2 = xv4[(it + 3) * 64 + lane];

        // local 4-element scan (zero entering state)
        float sx0 = s * xv.x, sx1 = s * xv.y, sx2 = s * xv.z, sx3 = s * xv.w;
        float B1 = fmaf(a, sx0, sx1);
        float B2 = fmaf(a, B1, sx2);
        float B3 = fmaf(a, B2, sx3);

        // pure-DPP weighted wave scan over lane composites (ratio a^4)
        float P = wave_scan(B3, c0, c1, c2, c3, w15, w31);

        float m3 = fmaf(a4l1, carry, P);           // true inclusive value at lane's elem 3
        carry = fmaf(a256, carry, lane63(P));      // scalar carry chain (v_readlane)

        if (it >= halo) {                          // wave-uniform branch
            // back-substitute: m_{j-1} = (m_j - s*x_j) / a
            float m2 = (m3 - sx3) * invA;
            float m1 = (m2 - sx2) * invA;
            float m0 = (m1 - sx1) * invA;
            vfloat4 o;
            o.x = pcen_out(xv.x, m0);
            o.y = pcen_out(xv.y, m1);
            o.z = pcen_out(xv.z, m2);
            o.w = pcen_out(xv.w, m3);
            __builtin_nontemporal_store(o, &ov4[it * 64 + lane]);
        }
    }

    // chunk 3 tail: 64 elements, t = 7936..7999, one per lane (ratio a)
    if (chunk == 3) {
        const float t15 = hw_exp2((float)(lm31 - 15) * l2a);  // a^((lane&31)-15)
        const float t31 = hw_exp2((float)(lane - 31) * l2a);  // a^(lane-31)
        const float al1 = hw_exp2((float)(lane + 1) * l2a);   // a^(lane+1)
        float xt = xp[7936 + lane];
        float P = wave_scan(s * xt, a, a2, a4, a4 * a4, t15, t31);
        float m = fmaf(al1, carry, P);
        op[7936 + lane] = pcen_out(xt, m);
    }
}

extern "C" void kernel_launch(void* const* d_in, const int* in_sizes, int n_in,
                              void* d_out, int out_size, void* d_ws, size_t ws_size,
                              hipStream_t stream) {
    const float* x     = (const float*)d_in[0];
    const float* log_s = (const float*)d_in[1];
    float*       out   = (float*)d_out;
    // 4096 seqs x 4 chunks = 16384 waves; 4 waves per 256-thread block
    pcen_kernel<<<dim3(NSEQ), dim3(256), 0, stream>>>(x, log_s, out);
}